// Round 1
// baseline (1405.419 us; speedup 1.0000x reference)
//
#include <hip/hip_runtime.h>
#include <stdint.h>

#define B_ 2
#define S_ 2048
#define H_ 2048
#define NH_ 16
#define NKV_ 4
#define DH_ 128
#define M_ (B_*S_)   // 4096 rows

typedef unsigned short u16;
typedef __attribute__((ext_vector_type(8))) short short8;
typedef __attribute__((ext_vector_type(4))) float floatx4;

__device__ __forceinline__ float b2f(u16 h) {
  union { unsigned int u; float f; } v; v.u = ((unsigned int)h) << 16; return v.f;
}
__device__ __forceinline__ u16 f2b(float f) {
  union { float f; unsigned int u; } v; v.f = f;
  unsigned int u = v.u;
  unsigned int r = (u + 0x7FFFu + ((u >> 16) & 1u)) >> 16;
  return (u16)r;
}
__device__ __forceinline__ floatx4 mfma16(short8 a, short8 b, floatx4 c) {
  return __builtin_amdgcn_mfma_f32_16x16x32_bf16(a, b, c, 0, 0, 0);
}
// async global->LDS, 16B per lane. LDS dest = wave-uniform base + lane*16.
__device__ __forceinline__ void gld16(const u16* g, u16* l) {
  __builtin_amdgcn_global_load_lds(
      (const __attribute__((address_space(1))) unsigned int*)g,
      (__attribute__((address_space(3))) unsigned int*)l, 16, 0, 0);
}

// ---- weight convert+transpose: f32 (K,N) -> bf16 (N,K), 64x64 tiles ------
__global__ __launch_bounds__(256) void transpose_kernel(const float* __restrict__ Bm,
                                                        u16* __restrict__ BT,
                                                        int K, int N) {
  __shared__ u16 sl[64][68];
  int t = threadIdx.x;
  int n0 = blockIdx.x * 64, k0 = blockIdx.y * 64;
#pragma unroll
  for (int p = 0; p < 4; ++p) {
    int kk = p * 16 + (t >> 4);
    int nn = (t & 15) * 4;
    float4 v = *(const float4*)&Bm[(size_t)(k0 + kk) * N + n0 + nn];
    sl[kk][nn + 0] = f2b(v.x); sl[kk][nn + 1] = f2b(v.y);
    sl[kk][nn + 2] = f2b(v.z); sl[kk][nn + 3] = f2b(v.w);
  }
  __syncthreads();
#pragma unroll
  for (int p = 0; p < 2; ++p) {
    int nn = p * 32 + (t >> 3);
    int kc = (t & 7) * 8;
    u16 ov[8];
#pragma unroll
    for (int j = 0; j < 8; ++j) ov[j] = sl[kc + j][nn];
    *(uint4*)&BT[(size_t)(n0 + nn) * K + k0 + kc] = *(uint4*)ov;
  }
}

// ---------------- RMSNorm over H=2048: f32 in, bf16 out. One row/block ----
__global__ __launch_bounds__(256) void rmsnorm_kernel(const float* __restrict__ x,
                                                      const float* __restrict__ w,
                                                      u16* __restrict__ o) {
  int row = blockIdx.x;
  int tid = threadIdx.x;
  const float* xr = x + (size_t)row * H_ + tid * 8;
  float4 a = *(const float4*)xr;
  float4 b = *(const float4*)(xr + 4);
  float xf[8] = {a.x, a.y, a.z, a.w, b.x, b.y, b.z, b.w};
  float ss = 0.f;
#pragma unroll
  for (int i = 0; i < 8; ++i) ss += xf[i] * xf[i];
#pragma unroll
  for (int m = 32; m >= 1; m >>= 1) ss += __shfl_xor(ss, m, 64);
  __shared__ float red[4];
  if ((tid & 63) == 0) red[tid >> 6] = ss;
  __syncthreads();
  float tot = red[0] + red[1] + red[2] + red[3];
  float scale = rsqrtf(tot / (float)H_ + 1e-6f);
  const float* wr = w + tid * 8;
  float4 wa = *(const float4*)wr;
  float4 wb = *(const float4*)(wr + 4);
  float wf[8] = {wa.x, wa.y, wa.z, wa.w, wb.x, wb.y, wb.z, wb.w};
  u16 ov[8];
#pragma unroll
  for (int i = 0; i < 8; ++i) ov[i] = f2b(xf[i] * scale * wf[i]);
  *(uint4*)&o[(size_t)row * H_ + tid * 8] = *(uint4*)ov;
}

// ---- pipelined GEMM: C(M,N) = A_bf16(M,K) @ BT_bf16(N,K)^T ---------------
// T3+T4+T2+T5: 256-row tiles, BK=32, ring-of-4 LDS buffers, staging leads
// compute by 3 K-tiles, counted vmcnt (never 0 in steady state), one raw
// s_barrier per K-tile, XOR-swizzled LDS (conflict-free ds_read_b128),
// setprio around MFMA clusters.
// BN=256: 8 waves as 2Mx4N, 128x64 per wave (acc 8x4).
// BN=128: 8 waves as 4Mx2N, 64x64 per wave (acc 4x4).
// OUTF: 0 = bf16 out; 1 = f32 out (+Res if non-null); 2 = in-place
//       silu-fuse: O[idx] = silu(acc) * bf16_O[idx]  (O = Cv, bf16).
template <int BN, int OUTF>
__global__ __launch_bounds__(512) void gemm_p(const u16* __restrict__ A,
                                              const u16* __restrict__ BT,
                                              void* __restrict__ Cv,
                                              const float* __restrict__ Res,
                                              int M, int N, int K) {
  constexpr int WN    = (BN == 256) ? 4 : 2;    // waves along N
  constexpr int WROWS = (BN == 256) ? 128 : 64; // rows per wave
  constexpr int AFRAG = WROWS / 16;
  constexpr int IPT   = 2 + BN / 128;           // gld16 issues per K-tile
  __shared__ __align__(16) u16 sa[4][256 * 32];
  __shared__ __align__(16) u16 sb[4][BN * 32];
  const int tid = threadIdx.x;
  const int lane = tid & 63, w = tid >> 6;
  const int q4 = lane >> 4, l15 = lane & 15;
  const int wm = w / WN, wn = w % WN;
  const int m0 = blockIdx.y * 256, n0 = blockIdx.x * BN;
  // staging: thread t covers LDS linear bytes [i*8192 + t*16, +16). That is
  // row = i*128 + (t>>2), physical 16B-block = t&3. Swizzle: phys = logical
  // ^ ((row>>1)&3), so the logical block fetched is (t&3)^((t>>3)&3).
  const int srow = tid >> 2;
  const int scb  = (tid & 3) ^ ((tid >> 3) & 3);
  const u16* aS = A  + (size_t)(m0 + srow) * K + scb * 8;
  const u16* bS = BT + (size_t)(n0 + srow) * K + scb * 8;
  const int lOff = w * 512;  // u16 offset of this wave's 1KB chunk per issue
  // ds_read side of the swizzle: rows base is a multiple of 16, so
  // ((row>>1)&3) == ((l15>>1)&3). Each quarter-wave lands 2 lanes per
  // 4-bank group -> free 2-way.
  const int colSwz = (q4 ^ ((l15 >> 1) & 3)) * 8;
  const int arow0 = wm * WROWS + l15;
  const int brow0 = wn * 64 + l15;
  const int NT = K / 32;
  floatx4 acc[AFRAG][4] = {};

  auto stage = [&](int tt) {
    const int bb = tt & 3;
    const int ko = tt * 32;
    gld16(aS + ko,                   &sa[bb][lOff]);
    gld16(aS + (size_t)128 * K + ko, &sa[bb][4096 + lOff]);
    gld16(bS + ko,                   &sb[bb][lOff]);
    if constexpr (BN == 256)
      gld16(bS + (size_t)128 * K + ko, &sb[bb][4096 + lOff]);
  };

  stage(0); stage(1); stage(2);
  for (int t = 0; t < NT; ++t) {
    const u16* sab = sa[t & 3];
    const u16* sbb = sb[t & 3];
    const int left = NT - 1 - t;
    // own issues for tile t landed; up to 2 newer tiles stay in flight
    if (left >= 2) {
      asm volatile("s_waitcnt vmcnt(%0)" :: "n"(2 * IPT) : "memory");
    } else if (left == 1) {
      asm volatile("s_waitcnt vmcnt(%0)" :: "n"(IPT) : "memory");
    } else {
      asm volatile("s_waitcnt vmcnt(0)" ::: "memory");
    }
    __builtin_amdgcn_s_barrier();
    asm volatile("" ::: "memory");   // keep LDS reads below the barrier
    if (t + 3 < NT) stage(t + 3);    // overwrites slot freed last iteration
    short8 bfr[4];
#pragma unroll
    for (int j = 0; j < 4; ++j)
      bfr[j] = *(const short8*)&sbb[(brow0 + j * 16) * 32 + colSwz];
#pragma unroll
    for (int ih = 0; ih < AFRAG / 4; ++ih) {
      short8 afr[4];
#pragma unroll
      for (int i2 = 0; i2 < 4; ++i2)
        afr[i2] = *(const short8*)&sab[(arow0 + (ih * 4 + i2) * 16) * 32 + colSwz];
      __builtin_amdgcn_s_setprio(1);
#pragma unroll
      for (int i2 = 0; i2 < 4; ++i2)
#pragma unroll
        for (int j = 0; j < 4; ++j)
          acc[ih * 4 + i2][j] = mfma16(afr[i2], bfr[j], acc[ih * 4 + i2][j]);
      __builtin_amdgcn_s_setprio(0);
    }
  }

#pragma unroll
  for (int i = 0; i < AFRAG; ++i)
#pragma unroll
    for (int j = 0; j < 4; ++j) {
      const int row0 = m0 + wm * WROWS + i * 16 + q4 * 4;
      const int col  = n0 + wn * 64 + j * 16 + l15;
#pragma unroll
      for (int r = 0; r < 4; ++r) {
        const size_t idx = (size_t)(row0 + r) * N + col;
        float v = acc[i][j][r];
        if constexpr (OUTF == 1) {
          if (Res) v += Res[idx];
          ((float*)Cv)[idx] = v;
        } else if constexpr (OUTF == 2) {
          u16* O = (u16*)Cv;
          float u = b2f(O[idx]);
          float s = v / (1.f + __expf(-v));
          O[idx] = f2b(s * u);
        } else {
          ((u16*)Cv)[idx] = f2b(v);
        }
      }
    }
}

// ------- per-head RMSNorm + RoPE (in place on bf16), 1 wave per (t,h) -----
__global__ __launch_bounds__(256) void qknorm_rope_kernel(u16* __restrict__ x,
                                                          const float* __restrict__ nw,
                                                          const float* __restrict__ cs,
                                                          const float* __restrict__ sn,
                                                          int nheads, int rowStride) {
  int lane = threadIdx.x & 63;
  int w = threadIdx.x >> 6;
  int gw = blockIdx.x * 4 + w;
  int t = gw / nheads, h = gw % nheads;
  u16* xp = x + (size_t)t * rowStride + h * DH_;
  float x0 = b2f(xp[lane]), x1 = b2f(xp[lane + 64]);
  float ss = x0 * x0 + x1 * x1;
#pragma unroll
  for (int m = 32; m >= 1; m >>= 1) ss += __shfl_xor(ss, m, 64);
  float scale = rsqrtf(ss / 128.f + 1e-6f);
  float n0 = x0 * scale * nw[lane];
  float n1 = x1 * scale * nw[lane + 64];
  const float* cp = cs + (size_t)t * DH_;
  const float* sp = sn + (size_t)t * DH_;
  float c0 = cp[lane], c1 = cp[lane + 64];
  float s0 = sp[lane], s1 = sp[lane + 64];
  xp[lane]      = f2b(n0 * c0 - n1 * s0);
  xp[lane + 64] = f2b(n1 * c1 + n0 * s1);
}

// ---------------- flash attention (full, non-causal), GQA, all bf16 -------
__global__ __launch_bounds__(256) void attn_kernel(const u16* __restrict__ qb,
                                                   const u16* __restrict__ kb,
                                                   const u16* __restrict__ vb,
                                                   u16* __restrict__ ob) {
  __shared__ u16 q_lds[64][136];
  __shared__ u16 k_lds[64][136];
  __shared__ u16 vt_lds[128][72];   // [d][j]
  __shared__ u16 p_lds[4][16][72];  // per wave [qrow][j]
  const int QSTR = NH_ * DH_ + NKV_ * DH_ * 2;  // 3072 row stride in qkv buffer
  int tid = threadIdx.x;
  int lane = tid & 63, w = tid >> 6;
  int q4 = lane >> 4, l15 = lane & 15;
  int qt = blockIdx.x & 31;
  int h = (blockIdx.x >> 5) & 15;
  int b = blockIdx.x >> 9;
  int kvh = h >> 2;
  int srow = tid >> 2;
  int sd0 = (tid & 3) * 32;
  const float scaling = 0.08838834764831845f;

  {
    const u16* qsrc = qb + (size_t)(b * S_ + qt * 64 + srow) * QSTR + h * DH_;
#pragma unroll
    for (int ii = 0; ii < 4; ++ii) {
      int d = sd0 + ii * 8;
      *(uint4*)&q_lds[srow][d] = *(const uint4*)&qsrc[d];
    }
  }

  float m_i[4], l_i[4];
  floatx4 o_acc[8] = {};
#pragma unroll
  for (int r = 0; r < 4; ++r) { m_i[r] = -1e30f; l_i[r] = 0.f; }

  for (int c = 0; c < S_ / 64; ++c) {
    int j0 = c * 64;
    __syncthreads();
    const u16* ksrc = kb + (size_t)(b * S_ + j0 + srow) * QSTR + kvh * DH_;
    const u16* vsrc = vb + (size_t)(b * S_ + j0 + srow) * QSTR + kvh * DH_;
#pragma unroll
    for (int ii = 0; ii < 4; ++ii) {
      int d = sd0 + ii * 8;
      *(uint4*)&k_lds[srow][d] = *(const uint4*)&ksrc[d];
      uint4 vv = *(const uint4*)&vsrc[d];
      const u16* ve = (const u16*)&vv;
#pragma unroll
      for (int e = 0; e < 8; ++e) vt_lds[d + e][srow] = ve[e];
    }
    __syncthreads();

    floatx4 sc[4];
#pragma unroll
    for (int js = 0; js < 4; ++js) {
      floatx4 a = {};
#pragma unroll
      for (int kk = 0; kk < 4; ++kk) {
        short8 qa  = *(const short8*)&q_lds[w * 16 + l15][kk * 32 + q4 * 8];
        short8 kbf = *(const short8*)&k_lds[js * 16 + l15][kk * 32 + q4 * 8];
        a = mfma16(qa, kbf, a);
      }
      sc[js] = a;
    }
    float mx[4];
#pragma unroll
    for (int r = 0; r < 4; ++r)
      mx[r] = fmaxf(fmaxf(sc[0][r], sc[1][r]), fmaxf(sc[2][r], sc[3][r])) * scaling;
#pragma unroll
    for (int m = 8; m >= 1; m >>= 1)
#pragma unroll
      for (int r = 0; r < 4; ++r) mx[r] = fmaxf(mx[r], __shfl_xor(mx[r], m, 64));
    float alpha[4], rs[4];
#pragma unroll
    for (int r = 0; r < 4; ++r) {
      float mnew = fmaxf(m_i[r], mx[r]);
      alpha[r] = __expf(m_i[r] - mnew);
      m_i[r] = mnew;
      rs[r] = 0.f;
    }
#pragma unroll
    for (int js = 0; js < 4; ++js)
#pragma unroll
      for (int r = 0; r < 4; ++r) {
        float p = __expf(sc[js][r] * scaling - m_i[r]);
        rs[r] += p;
        p_lds[w][q4 * 4 + r][js * 16 + l15] = f2b(p);
      }
#pragma unroll
    for (int m = 8; m >= 1; m >>= 1)
#pragma unroll
      for (int r = 0; r < 4; ++r) rs[r] += __shfl_xor(rs[r], m, 64);
#pragma unroll
    for (int r = 0; r < 4; ++r) l_i[r] = l_i[r] * alpha[r] + rs[r];
#pragma unroll
    for (int d2 = 0; d2 < 8; ++d2)
#pragma unroll
      for (int r = 0; r < 4; ++r) o_acc[d2][r] *= alpha[r];
    __syncthreads();
#pragma unroll
    for (int d2 = 0; d2 < 8; ++d2) {
#pragma unroll
      for (int kk = 0; kk < 2; ++kk) {
        short8 pa  = *(const short8*)&p_lds[w][l15][kk * 32 + q4 * 8];
        short8 vbf = *(const short8*)&vt_lds[d2 * 16 + l15][kk * 32 + q4 * 8];
        o_acc[d2] = mfma16(pa, vbf, o_acc[d2]);
      }
    }
  }
#pragma unroll
  for (int d2 = 0; d2 < 8; ++d2)
#pragma unroll
    for (int r = 0; r < 4; ++r) {
      int row = qt * 64 + w * 16 + q4 * 4 + r;
      float val = o_acc[d2][r] / l_i[r];
      ob[(size_t)(b * S_ + row) * (NH_ * DH_) + h * DH_ + d2 * 16 + l15] = f2b(val);
    }
}

extern "C" void kernel_launch(void* const* d_in, const int* in_sizes, int n_in,
                              void* d_out, int out_size, void* d_ws, size_t ws_size,
                              hipStream_t stream) {
  const float* hs   = (const float*)d_in[0];
  const float* cosb = (const float*)d_in[1];
  const float* sinb = (const float*)d_in[2];
  const float* wq   = (const float*)d_in[3];
  const float* wk   = (const float*)d_in[4];
  const float* wv   = (const float*)d_in[5];
  const float* wo   = (const float*)d_in[6];
  const float* qnw  = (const float*)d_in[7];
  const float* knw  = (const float*)d_in[8];
  const float* anw  = (const float*)d_in[9];
  const float* mnw  = (const float*)d_in[10];
  const float* wg   = (const float*)d_in[11];
  const float* wu   = (const float*)d_in[12];
  const float* wd   = (const float*)d_in[13];
  float* out = (float*)d_out;
  u16* ws  = (u16*)d_ws;

  // ws layout (u16 units), ~264 MB total
  u16* wqkvT = ws;                         //  6291456 (3072x2048: q rows 0-2047, k 2048-2559, v 2560-3071)
  u16* woT   = ws + 6291456;               //  4194304
  u16* wgT   = ws + 10485760;              // 16777216
  u16* wuT   = ws + 27262976;              // 16777216
  u16* wdT   = ws + 44040192;              // 16777216
  u16* xn    = ws + 60817408;              //  8388608 bf16 (rmsnorm1 out, later attn out)
  u16* qkv   = ws + 69206016;              // 12582912 bf16 (later reused as x2 = rmsnorm2 out)
  float* h1  = (float*)(ws + 81788928);    //  8388608 f32 (16777216 u16)
  u16* hbuf  = ws + 98566144;              // 33554432 bf16 (u, then silu(g)*u)

  // weight convert+transpose (f32 KxN -> bf16 NxK)
  transpose_kernel<<<dim3(2048/64, 2048/64), 256, 0, stream>>>(wq, wqkvT, 2048, 2048);
  transpose_kernel<<<dim3(512/64,  2048/64), 256, 0, stream>>>(wk, wqkvT + (size_t)2048*2048, 2048, 512);
  transpose_kernel<<<dim3(512/64,  2048/64), 256, 0, stream>>>(wv, wqkvT + (size_t)2560*2048, 2048, 512);
  transpose_kernel<<<dim3(2048/64, 2048/64), 256, 0, stream>>>(wo, woT, 2048, 2048);
  transpose_kernel<<<dim3(8192/64, 2048/64), 256, 0, stream>>>(wg, wgT, 2048, 8192);
  transpose_kernel<<<dim3(8192/64, 2048/64), 256, 0, stream>>>(wu, wuT, 2048, 8192);
  transpose_kernel<<<dim3(2048/64, 8192/64), 256, 0, stream>>>(wd, wdT, 8192, 2048);

  rmsnorm_kernel<<<M_, 256, 0, stream>>>(hs, anw, xn);
  gemm_p<256,0><<<dim3(3072/256, M_/256), 512, 0, stream>>>(xn, wqkvT, qkv, nullptr, M_, 3072, 2048);
  qknorm_rope_kernel<<<M_ * NH_  / 4, 256, 0, stream>>>(qkv,        qnw, cosb, sinb, NH_,  3072);
  qknorm_rope_kernel<<<M_ * NKV_ / 4, 256, 0, stream>>>(qkv + 2048, knw, cosb, sinb, NKV_, 3072);
  attn_kernel<<<B_ * NH_ * (S_ / 64), 256, 0, stream>>>(qkv, qkv + 2048, qkv + 2560, xn);
  gemm_p<128,1><<<dim3(2048/128, M_/256), 512, 0, stream>>>(xn, woT, h1, hs, M_, 2048, 2048);
  u16* x2 = qkv;  // qkv dead after wo GEMM
  rmsnorm_kernel<<<M_, 256, 0, stream>>>(h1, mnw, x2);
  gemm_p<256,0><<<dim3(8192/256, M_/256), 512, 0, stream>>>(x2, wuT, hbuf, nullptr, M_, 8192, 2048);  // u
  gemm_p<256,2><<<dim3(8192/256, M_/256), 512, 0, stream>>>(x2, wgT, hbuf, nullptr, M_, 8192, 2048);  // silu(g)*u in place
  gemm_p<128,1><<<dim3(2048/128, M_/256), 512, 0, stream>>>(hbuf, wdT, out, h1, M_, 2048, 8192);
}

// Round 2
// 1244.151 us; speedup vs baseline: 1.1296x; 1.1296x over previous
//
#include <hip/hip_runtime.h>
#include <stdint.h>

#define B_ 2
#define S_ 2048
#define H_ 2048
#define NH_ 16
#define NKV_ 4
#define DH_ 128
#define M_ (B_*S_)   // 4096 rows

typedef unsigned short u16;
typedef __attribute__((ext_vector_type(8))) short short8;
typedef __attribute__((ext_vector_type(4))) float floatx4;

__device__ __forceinline__ float b2f(u16 h) {
  union { unsigned int u; float f; } v; v.u = ((unsigned int)h) << 16; return v.f;
}
__device__ __forceinline__ u16 f2b(float f) {
  union { float f; unsigned int u; } v; v.f = f;
  unsigned int u = v.u;
  unsigned int r = (u + 0x7FFFu + ((u >> 16) & 1u)) >> 16;
  return (u16)r;
}
__device__ __forceinline__ floatx4 mfma16(short8 a, short8 b, floatx4 c) {
  return __builtin_amdgcn_mfma_f32_16x16x32_bf16(a, b, c, 0, 0, 0);
}
// async global->LDS, 16B per lane. LDS dest = wave-uniform base + lane*16.
__device__ __forceinline__ void gld16(const u16* g, u16* l) {
  __builtin_amdgcn_global_load_lds(
      (const __attribute__((address_space(1))) unsigned int*)g,
      (__attribute__((address_space(3))) unsigned int*)l, 16, 0, 0);
}

#define BAR()    asm volatile("s_barrier" ::: "memory")
#define LGKM0()  asm volatile("s_waitcnt lgkmcnt(0)" ::: "memory")
#define VMC(n)   asm volatile("s_waitcnt vmcnt(" #n ")" ::: "memory")
#define SCHEDB() __builtin_amdgcn_sched_barrier(0)
#define PRIO1()  __builtin_amdgcn_s_setprio(1)
#define PRIO0()  __builtin_amdgcn_s_setprio(0)

// ---- weight convert+transpose: f32 (K,N) -> bf16 (N,K), 64x64 tiles ------
// ileave: 0 = dense; 1 = gate rows (even 128-slot); 2 = up rows (odd slot).
__global__ __launch_bounds__(256) void transpose_kernel(const float* __restrict__ Bm,
                                                        u16* __restrict__ BT,
                                                        int K, int N, int ileave) {
  __shared__ u16 sl[64][68];
  int t = threadIdx.x;
  int n0 = blockIdx.x * 64, k0 = blockIdx.y * 64;
#pragma unroll
  for (int p = 0; p < 4; ++p) {
    int kk = p * 16 + (t >> 4);
    int nn = (t & 15) * 4;
    float4 v = *(const float4*)&Bm[(size_t)(k0 + kk) * N + n0 + nn];
    sl[kk][nn + 0] = f2b(v.x); sl[kk][nn + 1] = f2b(v.y);
    sl[kk][nn + 2] = f2b(v.z); sl[kk][nn + 3] = f2b(v.w);
  }
  __syncthreads();
#pragma unroll
  for (int p = 0; p < 2; ++p) {
    int nn = p * 32 + (t >> 3);
    int kc = (t & 7) * 8;
    u16 ov[8];
#pragma unroll
    for (int j = 0; j < 8; ++j) ov[j] = sl[kc + j][nn];
    int n = n0 + nn;
    int n_out = n;
    if (ileave) n_out = ((n >> 7) << 8) + ((ileave == 2) ? 128 : 0) + (n & 127);
    *(uint4*)&BT[(size_t)n_out * K + k0 + kc] = *(uint4*)ov;
  }
}

// ---------------- RMSNorm over H=2048: f32 in, bf16 out. One row/block ----
__global__ __launch_bounds__(256) void rmsnorm_kernel(const float* __restrict__ x,
                                                      const float* __restrict__ w,
                                                      u16* __restrict__ o) {
  int row = blockIdx.x;
  int tid = threadIdx.x;
  const float* xr = x + (size_t)row * H_ + tid * 8;
  float4 a = *(const float4*)xr;
  float4 b = *(const float4*)(xr + 4);
  float xf[8] = {a.x, a.y, a.z, a.w, b.x, b.y, b.z, b.w};
  float ss = 0.f;
#pragma unroll
  for (int i = 0; i < 8; ++i) ss += xf[i] * xf[i];
#pragma unroll
  for (int m = 32; m >= 1; m >>= 1) ss += __shfl_xor(ss, m, 64);
  __shared__ float red[4];
  if ((tid & 63) == 0) red[tid >> 6] = ss;
  __syncthreads();
  float tot = red[0] + red[1] + red[2] + red[3];
  float scale = rsqrtf(tot / (float)H_ + 1e-6f);
  const float* wr = w + tid * 8;
  float4 wa = *(const float4*)wr;
  float4 wb = *(const float4*)(wr + 4);
  float wf[8] = {wa.x, wa.y, wa.z, wa.w, wb.x, wb.y, wb.z, wb.w};
  u16 ov[8];
#pragma unroll
  for (int i = 0; i < 8; ++i) ov[i] = f2b(xf[i] * scale * wf[i]);
  *(uint4*)&o[(size_t)row * H_ + tid * 8] = *(uint4*)ov;
}

// ---- m97-style GEMM: C(M,N) = A_bf16(M,K) @ BT_bf16(N,K)^T [+Res_f32] ----
template <int OUTF>   // 0: bf16 out; 1: f32 out (+Res if non-null)
__global__ __launch_bounds__(256) void gemm_t(const u16* __restrict__ A,
                                              const u16* __restrict__ BT,
                                              void* __restrict__ Cv,
                                              const float* __restrict__ Res,
                                              int M, int N, int K) {
  __shared__ u16 sa[128 * 32];
  __shared__ u16 sb[128 * 32];
  const int tid = threadIdx.x;
  const int lane = tid & 63, w = tid >> 6;
  const int q4 = lane >> 4, l15 = lane & 15;
  const int wr = (w >> 1) * 64, wc = (w & 1) * 64;
  const int m0 = blockIdx.y * 128, n0 = blockIdx.x * 128;
  const int srow = lane >> 2, skc = (lane & 3) * 8;
  const int c0 = w * 2;
  floatx4 acc[4][4] = {};
  const u16* aG0 = A  + (size_t)(m0 + (c0 + 0) * 16 + srow) * K + skc;
  const u16* aG1 = A  + (size_t)(m0 + (c0 + 1) * 16 + srow) * K + skc;
  const u16* bG0 = BT + (size_t)(n0 + (c0 + 0) * 16 + srow) * K + skc;
  const u16* bG1 = BT + (size_t)(n0 + (c0 + 1) * 16 + srow) * K + skc;
  u16* aL0 = sa + (c0 + 0) * 512;
  u16* aL1 = sa + (c0 + 1) * 512;
  u16* bL0 = sb + (c0 + 0) * 512;
  u16* bL1 = sb + (c0 + 1) * 512;

  for (int k0 = 0; k0 < K; k0 += 32) {
    __syncthreads();
    gld16(aG0 + k0, aL0);
    gld16(aG1 + k0, aL1);
    gld16(bG0 + k0, bL0);
    gld16(bG1 + k0, bL1);
    __syncthreads();
    short8 af[4], bf[4];
#pragma unroll
    for (int i = 0; i < 4; ++i)
      af[i] = *(const short8*)&sa[(wr + i * 16 + l15) * 32 + q4 * 8];
#pragma unroll
    for (int j = 0; j < 4; ++j)
      bf[j] = *(const short8*)&sb[(wc + j * 16 + l15) * 32 + q4 * 8];
#pragma unroll
    for (int i = 0; i < 4; ++i)
#pragma unroll
      for (int j = 0; j < 4; ++j)
        acc[i][j] = mfma16(af[i], bf[j], acc[i][j]);
  }
#pragma unroll
  for (int i = 0; i < 4; ++i)
#pragma unroll
    for (int j = 0; j < 4; ++j)
#pragma unroll
      for (int r = 0; r < 4; ++r) {
        int row = m0 + wr + i * 16 + q4 * 4 + r;
        int col = n0 + wc + j * 16 + l15;
        float v = acc[i][j][r];
        if (OUTF) {
          if (Res) v += Res[(size_t)row * N + col];
          ((float*)Cv)[(size_t)row * N + col] = v;
        } else {
          ((u16*)Cv)[(size_t)row * N + col] = f2b(v);
        }
      }
}

// ---- 8-phase 256x256 GEMM (m201-style): C = A_bf16(M,K) @ BT_bf16(N,K)^T -
// 8 waves (2M x 4N), BK=64, dbuf LDS (128 KB), per phase: {ds-reads, stages,
// barrier, lgkmcnt(0), setprio, 16 MFMA (one C-quadrant), barrier}. Counted
// vmcnt(8) once per K-tile. LDS XOR-swizzle (both-sides, rule #21): linear
// gld_lds dest + inverse-swizzled global source + swizzled ds_read.
// Stage ordering is barrier-safe: B-halves of tile t+2 staged only after
// both B-read phases of tile t; A-halves after both A-read phases.
// OUTF: 0 = bf16 out (ld = ldO); 3 = gateup: BT rows interleave 128 g-rows /
//       128 u-rows per 256; epilogue exchanges u via LDS, writes silu(g)*u.
template <int OUTF>
__global__ __launch_bounds__(512, 2) void gemm8(const u16* __restrict__ A,
                                                const u16* __restrict__ BT,
                                                void* __restrict__ Cv,
                                                int M, int N, int K,
                                                int gm, int ldO) {
  __shared__ u16 sA[2][2][8192];   // [dbuf][half: 128 rows][row*64 + col]
  __shared__ u16 sB[2][2][8192];
  const int tid = threadIdx.x;
  const int lane = tid & 63, w = tid >> 6;
  const int q4 = lane >> 4, l15 = lane & 15;
  const int wm = w >> 2, wn = w & 3;         // 2M x 4N
  // bijective XCD-aware raster (m204), m-fastest within XCD chunk
  const int nwg = gridDim.x;
  const int qx = nwg >> 3, rx = nwg & 7;
  const int xcd = blockIdx.x & 7, idxx = blockIdx.x >> 3;
  const int wgid = (xcd < rx ? xcd * (qx + 1) : rx * (qx + 1) + (xcd - rx) * qx) + idxx;
  const int m0 = (wgid % gm) * 256, n0 = (wgid / gm) * 256;

  // staging source (pre-swizzled global address; LDS dest stays linear)
  const int sr = tid >> 3;                          // 0..63 row within 64-row chunk
  const int sblk = ((tid & 7) ^ (sr & 7)) << 3;     // logical 8-col block
  const u16* aS = A  + (size_t)(m0 + sr) * K + sblk;
  const u16* bS = BT + (size_t)(n0 + sr) * K + sblk;
  const size_t K64 = (size_t)K << 6;                // 64 rows stride
  const int wofs = w * 512;

  // ds_read swizzle: phys 8-col block = (s*4+q4) ^ (l15&7)
  const int cA  = (q4 ^ (l15 & 7)) << 3;            // s=0 col offset (u16)
  const int bh  = wn >> 1;                          // B half
  const int bb  = (wn & 1) * 64;                    // B row base within half
  const int NT  = K >> 6;

  floatx4 acc[8][4] = {};

  auto stA = [&](int c, int k0) {
    const u16* s0 = aS + k0;
    gld16(s0,            &sA[c][0][wofs]);
    gld16(s0 + K64,      &sA[c][0][4096 + wofs]);
    gld16(s0 + 2 * K64,  &sA[c][1][wofs]);
    gld16(s0 + 3 * K64,  &sA[c][1][4096 + wofs]);
  };
  auto stB = [&](int c, int k0) {
    const u16* s0 = bS + k0;
    gld16(s0,            &sB[c][0][wofs]);
    gld16(s0 + K64,      &sB[c][0][4096 + wofs]);
    gld16(s0 + 2 * K64,  &sB[c][1][wofs]);
    gld16(s0 + 3 * K64,  &sB[c][1][4096 + wofs]);
  };

  // prologue: tiles 0 and 1 fully staged; wait tile 0 (tile 1 floats)
  stB(0, 0); stA(0, 0);
  stB(1, 64); stA(1, 64);
  VMC(8);
  BAR();

  short8 aR[4][2], bR[4][2];
#pragma unroll 1
  for (int t = 0; t < NT; ++t) {
    const int c = t & 1;
    const u16* aH = &sA[c][wm][0];
    const u16* bH = &sB[c][bh][0];
    const bool pf = (t + 2 < NT);
    const int kp = (t + 2) << 6;

    // ---- phase 1: ds a[0..3] + b[0..1]; MFMA Q(0,0)
#pragma unroll
    for (int i = 0; i < 4; ++i) {
      const int ro = (i * 16 + l15) * 64;
      aR[i][0] = *(const short8*)&aH[ro + cA];
      aR[i][1] = *(const short8*)&aH[ro + (cA ^ 32)];
    }
#pragma unroll
    for (int j = 0; j < 2; ++j) {
      const int ro = (bb + j * 16 + l15) * 64;
      bR[j][0] = *(const short8*)&bH[ro + cA];
      bR[j][1] = *(const short8*)&bH[ro + (cA ^ 32)];
    }
    BAR(); LGKM0(); SCHEDB();
    PRIO1();
#pragma unroll
    for (int i = 0; i < 4; ++i)
#pragma unroll
      for (int j = 0; j < 2; ++j) {
        acc[i][j] = mfma16(aR[i][0], bR[j][0], acc[i][j]);
        acc[i][j] = mfma16(aR[i][1], bR[j][1], acc[i][j]);
      }
    PRIO0();
    BAR();

    // ---- phase 2: ds b[2..3]; MFMA Q(0,1)
#pragma unroll
    for (int j = 2; j < 4; ++j) {
      const int ro = (bb + j * 16 + l15) * 64;
      bR[j][0] = *(const short8*)&bH[ro + cA];
      bR[j][1] = *(const short8*)&bH[ro + (cA ^ 32)];
    }
    BAR(); LGKM0(); SCHEDB();
    PRIO1();
#pragma unroll
    for (int i = 0; i < 4; ++i)
#pragma unroll
      for (int j = 2; j < 4; ++j) {
        acc[i][j] = mfma16(aR[i][0], bR[j][0], acc[i][j]);
        acc[i][j] = mfma16(aR[i][1], bR[j][1], acc[i][j]);
      }
    PRIO0();
    BAR();

    // ---- phase 3: ds a[4..7] (reuse regs); stage t+2 B; MFMA Q(1,1)
#pragma unroll
    for (int i = 0; i < 4; ++i) {
      const int ro = ((i + 4) * 16 + l15) * 64;
      aR[i][0] = *(const short8*)&aH[ro + cA];
      aR[i][1] = *(const short8*)&aH[ro + (cA ^ 32)];
    }
    if (pf) stB(c, kp);   // safe: all B reads of buf c completed (barriers)
    BAR(); LGKM0(); SCHEDB();
    PRIO1();
#pragma unroll
    for (int i = 0; i < 4; ++i)
#pragma unroll
      for (int j = 2; j < 4; ++j) {
        acc[i + 4][j] = mfma16(aR[i][0], bR[j][0], acc[i + 4][j]);
        acc[i + 4][j] = mfma16(aR[i][1], bR[j][1], acc[i + 4][j]);
      }
    PRIO0();
    BAR();

    // ---- phase 4: stage t+2 A; counted vmcnt; MFMA Q(1,0)
    if (pf) stA(c, kp);   // safe: all A reads of buf c completed (barriers)
    if (pf) { VMC(8); }              // tile t+1 fully landed; t+2 floats
    else if (t + 1 < NT) { VMC(0); } // drain tail (cheap, loads are old)
    BAR(); SCHEDB();
    PRIO1();
#pragma unroll
    for (int i = 0; i < 4; ++i)
#pragma unroll
      for (int j = 0; j < 2; ++j) {
        acc[i + 4][j] = mfma16(aR[i][0], bR[j][0], acc[i + 4][j]);
        acc[i + 4][j] = mfma16(aR[i][1], bR[j][1], acc[i + 4][j]);
      }
    PRIO0();
    BAR();
  }

  if constexpr (OUTF == 0) {
#pragma unroll
    for (int i = 0; i < 8; ++i)
#pragma unroll
      for (int j = 0; j < 4; ++j)
#pragma unroll
        for (int r = 0; r < 4; ++r) {
          const int row = m0 + wm * 128 + i * 16 + q4 * 4 + r;
          const int col = n0 + wn * 64 + j * 16 + l15;
          ((u16*)Cv)[(size_t)row * ldO + col] = f2b(acc[i][j][r]);
        }
  } else {  // gateup: wn<2 hold g-cols, wn>=2 hold u-cols of the same strip
    u16* X = &sA[0][0][0];   // 64 KB: [wm*128+rl][128]
    __syncthreads();
    if (wn >= 2) {
#pragma unroll
      for (int i = 0; i < 8; ++i)
#pragma unroll
        for (int j = 0; j < 4; ++j)
#pragma unroll
          for (int r = 0; r < 4; ++r) {
            const int rl = i * 16 + q4 * 4 + r;
            const int uc = (wn - 2) * 64 + j * 16 + l15;
            X[(size_t)(wm * 128 + rl) * 128 + uc] = f2b(acc[i][j][r]);
          }
    }
    __syncthreads();
    if (wn < 2) {
#pragma unroll
      for (int i = 0; i < 8; ++i)
#pragma unroll
        for (int j = 0; j < 4; ++j)
#pragma unroll
          for (int r = 0; r < 4; ++r) {
            const int rl = i * 16 + q4 * 4 + r;
            const int gc = wn * 64 + j * 16 + l15;
            float g = acc[i][j][r];
            float u = b2f(X[(size_t)(wm * 128 + rl) * 128 + gc]);
            float s = g / (1.f + __expf(-g));
            const int row = m0 + wm * 128 + rl;
            const int ocol = (n0 >> 1) + gc;
            ((u16*)Cv)[(size_t)row * ldO + ocol] = f2b(s * u);
          }
    }
  }
}

// ------- per-head RMSNorm + RoPE (in place on bf16), 1 wave per (t,h) -----
__global__ __launch_bounds__(256) void qknorm_rope_kernel(u16* __restrict__ x,
                                                          const float* __restrict__ nw,
                                                          const float* __restrict__ cs,
                                                          const float* __restrict__ sn,
                                                          int nheads, int rowStride) {
  int lane = threadIdx.x & 63;
  int w = threadIdx.x >> 6;
  int gw = blockIdx.x * 4 + w;
  int t = gw / nheads, h = gw % nheads;
  u16* xp = x + (size_t)t * rowStride + h * DH_;
  float x0 = b2f(xp[lane]), x1 = b2f(xp[lane + 64]);
  float ss = x0 * x0 + x1 * x1;
#pragma unroll
  for (int m = 32; m >= 1; m >>= 1) ss += __shfl_xor(ss, m, 64);
  float scale = rsqrtf(ss / 128.f + 1e-6f);
  float n0 = x0 * scale * nw[lane];
  float n1 = x1 * scale * nw[lane + 64];
  const float* cp = cs + (size_t)t * DH_;
  const float* sp = sn + (size_t)t * DH_;
  float c0 = cp[lane], c1 = cp[lane + 64];
  float s0 = sp[lane], s1 = sp[lane + 64];
  xp[lane]      = f2b(n0 * c0 - n1 * s0);
  xp[lane + 64] = f2b(n1 * c1 + n0 * s1);
}

// ---------------- flash attention (full, non-causal), GQA, all bf16 -------
__global__ __launch_bounds__(256) void attn_kernel(const u16* __restrict__ qb,
                                                   const u16* __restrict__ kb,
                                                   const u16* __restrict__ vb,
                                                   u16* __restrict__ ob) {
  __shared__ u16 q_lds[64][136];
  __shared__ u16 k_lds[64][136];
  __shared__ u16 vt_lds[128][72];   // [d][j]
  __shared__ u16 p_lds[4][16][72];  // per wave [qrow][j]
  const int QSTR = NH_ * DH_ + NKV_ * DH_ * 2;  // 3072 row stride in qkv buffer
  int tid = threadIdx.x;
  int lane = tid & 63, w = tid >> 6;
  int q4 = lane >> 4, l15 = lane & 15;
  int qt = blockIdx.x & 31;
  int h = (blockIdx.x >> 5) & 15;
  int b = blockIdx.x >> 9;
  int kvh = h >> 2;
  int srow = tid >> 2;
  int sd0 = (tid & 3) * 32;
  const float scaling = 0.08838834764831845f;

  {
    const u16* qsrc = qb + (size_t)(b * S_ + qt * 64 + srow) * QSTR + h * DH_;
#pragma unroll
    for (int ii = 0; ii < 4; ++ii) {
      int d = sd0 + ii * 8;
      *(uint4*)&q_lds[srow][d] = *(const uint4*)&qsrc[d];
    }
  }

  float m_i[4], l_i[4];
  floatx4 o_acc[8] = {};
#pragma unroll
  for (int r = 0; r < 4; ++r) { m_i[r] = -1e30f; l_i[r] = 0.f; }

  for (int c = 0; c < S_ / 64; ++c) {
    int j0 = c * 64;
    __syncthreads();
    const u16* ksrc = kb + (size_t)(b * S_ + j0 + srow) * QSTR + kvh * DH_;
    const u16* vsrc = vb + (size_t)(b * S_ + j0 + srow) * QSTR + kvh * DH_;
#pragma unroll
    for (int ii = 0; ii < 4; ++ii) {
      int d = sd0 + ii * 8;
      *(uint4*)&k_lds[srow][d] = *(const uint4*)&ksrc[d];
      uint4 vv = *(const uint4*)&vsrc[d];
      const u16* ve = (const u16*)&vv;
#pragma unroll
      for (int e = 0; e < 8; ++e) vt_lds[d + e][srow] = ve[e];
    }
    __syncthreads();

    floatx4 sc[4];
#pragma unroll
    for (int js = 0; js < 4; ++js) {
      floatx4 a = {};
#pragma unroll
      for (int kk = 0; kk < 4; ++kk) {
        short8 qa  = *(const short8*)&q_lds[w * 16 + l15][kk * 32 + q4 * 8];
        short8 kbf = *(const short8*)&k_lds[js * 16 + l15][kk * 32 + q4 * 8];
        a = mfma16(qa, kbf, a);
      }
      sc[js] = a;
    }
    float mx[4];
#pragma unroll
    for (int r = 0; r < 4; ++r)
      mx[r] = fmaxf(fmaxf(sc[0][r], sc[1][r]), fmaxf(sc[2][r], sc[3][r])) * scaling;
#pragma unroll
    for (int m = 8; m >= 1; m >>= 1)
#pragma unroll
      for (int r = 0; r < 4; ++r) mx[r] = fmaxf(mx[r], __shfl_xor(mx[r], m, 64));
    float alpha[4], rs[4];
#pragma unroll
    for (int r = 0; r < 4; ++r) {
      float mnew = fmaxf(m_i[r], mx[r]);
      alpha[r] = __expf(m_i[r] - mnew);
      m_i[r] = mnew;
      rs[r] = 0.f;
    }
#pragma unroll
    for (int js = 0; js < 4; ++js)
#pragma unroll
      for (int r = 0; r < 4; ++r) {
        float p = __expf(sc[js][r] * scaling - m_i[r]);
        rs[r] += p;
        p_lds[w][q4 * 4 + r][js * 16 + l15] = f2b(p);
      }
#pragma unroll
    for (int m = 8; m >= 1; m >>= 1)
#pragma unroll
      for (int r = 0; r < 4; ++r) rs[r] += __shfl_xor(rs[r], m, 64);
#pragma unroll
    for (int r = 0; r < 4; ++r) l_i[r] = l_i[r] * alpha[r] + rs[r];
#pragma unroll
    for (int d2 = 0; d2 < 8; ++d2)
#pragma unroll
      for (int r = 0; r < 4; ++r) o_acc[d2][r] *= alpha[r];
    __syncthreads();
#pragma unroll
    for (int d2 = 0; d2 < 8; ++d2) {
#pragma unroll
      for (int kk = 0; kk < 2; ++kk) {
        short8 pa  = *(const short8*)&p_lds[w][l15][kk * 32 + q4 * 8];
        short8 vbf = *(const short8*)&vt_lds[d2 * 16 + l15][kk * 32 + q4 * 8];
        o_acc[d2] = mfma16(pa, vbf, o_acc[d2]);
      }
    }
  }
#pragma unroll
  for (int d2 = 0; d2 < 8; ++d2)
#pragma unroll
    for (int r = 0; r < 4; ++r) {
      int row = qt * 64 + w * 16 + q4 * 4 + r;
      float val = o_acc[d2][r] / l_i[r];
      ob[(size_t)(b * S_ + row) * (NH_ * DH_) + h * DH_ + d2 * 16 + l15] = f2b(val);
    }
}

extern "C" void kernel_launch(void* const* d_in, const int* in_sizes, int n_in,
                              void* d_out, int out_size, void* d_ws, size_t ws_size,
                              hipStream_t stream) {
  const float* hs   = (const float*)d_in[0];
  const float* cosb = (const float*)d_in[1];
  const float* sinb = (const float*)d_in[2];
  const float* wq   = (const float*)d_in[3];
  const float* wk   = (const float*)d_in[4];
  const float* wv   = (const float*)d_in[5];
  const float* wo   = (const float*)d_in[6];
  const float* qnw  = (const float*)d_in[7];
  const float* knw  = (const float*)d_in[8];
  const float* anw  = (const float*)d_in[9];
  const float* mnw  = (const float*)d_in[10];
  const float* wg   = (const float*)d_in[11];
  const float* wu   = (const float*)d_in[12];
  const float* wd   = (const float*)d_in[13];
  float* out = (float*)d_out;
  u16* ws  = (u16*)d_ws;

  // ws layout (u16 units), ~264 MB total
  u16* wqkvT = ws;                         //  6291456 (3072x2048: q rows 0-2047, k 2048-2559, v 2560-3071)
  u16* woT   = ws + 6291456;               //  4194304
  u16* wguT  = ws + 10485760;              // 33554432 (16384x2048 interleaved g/u)
  u16* wdT   = ws + 44040192;              // 16777216
  u16* xn    = ws + 60817408;              //  8388608 bf16 (rmsnorm1 out, later attn out)
  u16* qkv   = ws + 69206016;              // 12582912 bf16 (later reused as x2 = rmsnorm2 out)
  float* h1  = (float*)(ws + 81788928);    //  8388608 f32 (16777216 u16)
  u16* hbuf  = ws + 98566144;              // 33554432 bf16 (silu(g)*u)

  // weight convert+transpose (f32 KxN -> bf16 NxK)
  transpose_kernel<<<dim3(2048/64, 2048/64), 256, 0, stream>>>(wq, wqkvT, 2048, 2048, 0);
  transpose_kernel<<<dim3(512/64,  2048/64), 256, 0, stream>>>(wk, wqkvT + (size_t)2048*2048, 2048, 512, 0);
  transpose_kernel<<<dim3(512/64,  2048/64), 256, 0, stream>>>(wv, wqkvT + (size_t)2560*2048, 2048, 512, 0);
  transpose_kernel<<<dim3(2048/64, 2048/64), 256, 0, stream>>>(wo, woT, 2048, 2048, 0);
  transpose_kernel<<<dim3(8192/64, 2048/64), 256, 0, stream>>>(wg, wguT, 2048, 8192, 1);
  transpose_kernel<<<dim3(8192/64, 2048/64), 256, 0, stream>>>(wu, wguT, 2048, 8192, 2);
  transpose_kernel<<<dim3(2048/64, 8192/64), 256, 0, stream>>>(wd, wdT, 8192, 2048, 0);

  rmsnorm_kernel<<<M_, 256, 0, stream>>>(hs, anw, xn);
  // qkv: 8-phase 256^2, grid 16m x 12n = 192
  gemm8<0><<<16 * 12, 512, 0, stream>>>(xn, wqkvT, qkv, M_, 3072, 2048, 16, 3072);
  qknorm_rope_kernel<<<M_ * NH_  / 4, 256, 0, stream>>>(qkv,        qnw, cosb, sinb, NH_,  3072);
  qknorm_rope_kernel<<<M_ * NKV_ / 4, 256, 0, stream>>>(qkv + 2048, knw, cosb, sinb, NKV_, 3072);
  attn_kernel<<<B_ * NH_ * (S_ / 64), 256, 0, stream>>>(qkv, qkv + 2048, qkv + 2560, xn);
  gemm_t<1><<<dim3(2048/128, M_/128), 256, 0, stream>>>(xn, woT, h1, hs, M_, 2048, 2048);
  u16* x2 = qkv;  // qkv dead after wo GEMM
  rmsnorm_kernel<<<M_, 256, 0, stream>>>(h1, mnw, x2);
  // fused gate+up: 8-phase, BT rows = 16384 interleaved, grid 16m x 64n = 1024
  gemm8<3><<<16 * 64, 512, 0, stream>>>(x2, wguT, hbuf, M_, 16384, 2048, 16, 8192);
  gemm_t<1><<<dim3(2048/128, M_/128), 256, 0, stream>>>(hbuf, wdT, out, h1, M_, 2048, 8192);
}